// Round 2
// baseline (318.561 us; speedup 1.0000x reference)
//
#include <hip/hip_runtime.h>

#define NB 4096
#define NM 64
#define ND 64
#define NK 256

#define IDX_BASE 16777216UL   // 4096*64*64
#define LOSS_IDX 17039360UL   // IDX_BASE + 4096*64

// ---- tiny precompute: c2[m][k] = ||codebook[m][k]||^2 ----
__global__ __launch_bounds__(256) void pq_c2(const float* __restrict__ cb,
                                             float* __restrict__ c2) {
    int m = blockIdx.x, k = threadIdx.x;
    const float4* row = reinterpret_cast<const float4*>(cb + ((size_t)m * NK + k) * ND);
    float s0 = 0.f, s1 = 0.f;
    #pragma unroll
    for (int ch = 0; ch < 16; ch += 2) {
        float4 a = row[ch], b = row[ch + 1];
        s0 = fmaf(a.x, a.x, s0); s0 = fmaf(a.y, a.y, s0);
        s0 = fmaf(a.z, a.z, s0); s0 = fmaf(a.w, a.w, s0);
        s1 = fmaf(b.x, b.x, s1); s1 = fmaf(b.y, b.y, s1);
        s1 = fmaf(b.z, b.z, s1); s1 = fmaf(b.w, b.w, s1);
    }
    c2[m * NK + k] = s0 + s1;
}

// ---- main: wave = 64 rows (one per lane), z in registers, codes streamed
//      via wave-uniform loads (scalar/L1 pipe). No LDS in the hot loop. ----
__global__ __launch_bounds__(512, 4) void pq_main(
    const float* __restrict__ z, const float* __restrict__ cb,
    const float* __restrict__ c2ws,
    float* __restrict__ out, float* __restrict__ partial)
{
    const int tid  = threadIdx.x;
    const int bx   = blockIdx.x;
    const int m    = bx >> 3;          // 8 chunks per m (consecutive blocks share codebook)
    const int chnk = bx & 7;
    const int w    = tid >> 6;
    const int lane = tid & 63;
    const int R    = chnk * 512 + w * 64 + lane;   // global row (b index)

    const float* __restrict__ cbm = cb + (size_t)m * (NK * ND);
    const float* __restrict__ c2m = c2ws + m * NK;

    // z row -> 64 VGPRs, kept live for the whole kernel
    float4 zr[16];
    {
        const float4* zp4 = reinterpret_cast<const float4*>(z + ((size_t)R * NM + m) * ND);
        #pragma unroll
        for (int ch = 0; ch < 16; ++ch) zr[ch] = zp4[ch];
    }

    float best = 3.4e38f;
    int   bestk = 0;

    #pragma unroll 2
    for (int k = 0; k < NK; ++k) {
        const float4* ck = reinterpret_cast<const float4*>(cbm + k * ND);  // wave-uniform
        float a0 = 0.f, a1 = 0.f;
        #pragma unroll
        for (int ch = 0; ch < 16; ch += 2) {
            float4 c0 = ck[ch], c1 = ck[ch + 1];
            a0 = fmaf(zr[ch].x,     c0.x, a0);
            a0 = fmaf(zr[ch].y,     c0.y, a0);
            a0 = fmaf(zr[ch].z,     c0.z, a0);
            a0 = fmaf(zr[ch].w,     c0.w, a0);
            a1 = fmaf(zr[ch + 1].x, c1.x, a1);
            a1 = fmaf(zr[ch + 1].y, c1.y, a1);
            a1 = fmaf(zr[ch + 1].z, c1.z, a1);
            a1 = fmaf(zr[ch + 1].w, c1.w, a1);
        }
        float dist = fmaf(-2.0f, a0 + a1, c2m[k]);   // z2 omitted (row-constant)
        if (dist < best) { best = dist; bestk = k; } // strict < => first-min tiebreak
    }

    // ---- outputs ----
    out[IDX_BASE + (size_t)R * NM + m] = (float)bestk;

    const float4* qrow = reinterpret_cast<const float4*>(cbm + (size_t)bestk * ND);
    float4* orow = reinterpret_cast<float4*>(out + ((size_t)R * NM + m) * ND);
    float lsum = 0.f;
    #pragma unroll
    for (int ch = 0; ch < 16; ++ch) {
        float4 q  = qrow[ch];           // L2-hot gather (exact codebook copy)
        float4 zv = zr[ch];
        orow[ch] = q;
        float d;
        d = q.x - zv.x; lsum = fmaf(d, d, lsum);
        d = q.y - zv.y; lsum = fmaf(d, d, lsum);
        d = q.z - zv.z; lsum = fmaf(d, d, lsum);
        d = q.w - zv.w; lsum = fmaf(d, d, lsum);
    }

    // deterministic loss partial: wave reduce -> block reduce -> partial[bx]
    #pragma unroll
    for (int off = 1; off < 64; off <<= 1) lsum += __shfl_xor(lsum, off, 64);
    __shared__ float sW[8];
    if (lane == 0) sW[w] = lsum;
    __syncthreads();
    if (tid == 0) {
        float t = 0.f;
        #pragma unroll
        for (int i = 0; i < 8; ++i) t += sW[i];
        partial[bx] = t;
    }
}

// ---- deterministic final reduction of 512 block partials -> q_loss ----
__global__ __launch_bounds__(256) void pq_loss(const float* __restrict__ partial,
                                               float* __restrict__ out)
{
    __shared__ float sW[4];
    float s = partial[threadIdx.x] + partial[threadIdx.x + 256];
    #pragma unroll
    for (int off = 1; off < 64; off <<= 1) s += __shfl_xor(s, off, 64);
    if ((threadIdx.x & 63) == 0) sW[threadIdx.x >> 6] = s;
    __syncthreads();
    if (threadIdx.x == 0)
        out[LOSS_IDX] = (sW[0] + sW[1] + sW[2] + sW[3]) * (1.25f / 16777216.0f);
}

extern "C" void kernel_launch(void* const* d_in, const int* in_sizes, int n_in,
                              void* d_out, int out_size, void* d_ws, size_t ws_size,
                              hipStream_t stream) {
    const float* zp  = (const float*)d_in[0];
    const float* cbp = (const float*)d_in[1];
    float* outp = (float*)d_out;
    float* c2ws = (float*)d_ws;                 // 64*256 floats = 64 KB
    float* part = (float*)d_ws + NM * NK;       // 512 floats

    pq_c2  <<<dim3(64),  dim3(256), 0, stream>>>(cbp, c2ws);
    pq_main<<<dim3(512), dim3(512), 0, stream>>>(zp, cbp, c2ws, outp, part);
    pq_loss<<<dim3(1),   dim3(256), 0, stream>>>(part, outp);
}

// Round 3
// 255.940 us; speedup vs baseline: 1.2447x; 1.2447x over previous
//
#include <hip/hip_runtime.h>

#define IDX_BASE 16777216UL   // 4096*64*64
#define LOSS_IDX 17039360UL   // IDX_BASE + 4096*64

typedef float4 f4;

// Consume one quarter (16 dims) of code row k against resident z quarter.
#define QCONS(BUF, Z0) \
    a0 = fmaf(zv[Z0+0].x, BUF[0].x, a0); a0 = fmaf(zv[Z0+0].y, BUF[0].y, a0); \
    a0 = fmaf(zv[Z0+0].z, BUF[0].z, a0); a0 = fmaf(zv[Z0+0].w, BUF[0].w, a0); \
    a1 = fmaf(zv[Z0+1].x, BUF[1].x, a1); a1 = fmaf(zv[Z0+1].y, BUF[1].y, a1); \
    a1 = fmaf(zv[Z0+1].z, BUF[1].z, a1); a1 = fmaf(zv[Z0+1].w, BUF[1].w, a1); \
    a2 = fmaf(zv[Z0+2].x, BUF[2].x, a2); a2 = fmaf(zv[Z0+2].y, BUF[2].y, a2); \
    a2 = fmaf(zv[Z0+2].z, BUF[2].z, a2); a2 = fmaf(zv[Z0+2].w, BUF[2].w, a2); \
    a3 = fmaf(zv[Z0+3].x, BUF[3].x, a3); a3 = fmaf(zv[Z0+3].y, BUF[3].y, a3); \
    a3 = fmaf(zv[Z0+3].z, BUF[3].z, a3); a3 = fmaf(zv[Z0+3].w, BUF[3].w, a3);

// Refill quarter BUF with the next code row's quarter at float4 offset OFF.
#define QLOAD(BUF, OFF) \
    BUF[0] = nx[OFF+0]; BUF[1] = nx[OFF+1]; BUF[2] = nx[OFF+2]; BUF[3] = nx[OFF+3];

__global__ __launch_bounds__(256, 3) void pq_main(
    const float* __restrict__ z, const float* __restrict__ cb,
    float* __restrict__ out, float* __restrict__ partial)
{
    __shared__ float sC2[256];
    __shared__ float sW[4];

    const int tid   = threadIdx.x;
    const int bx    = blockIdx.x;
    const int w     = tid >> 6;
    const int lane  = tid & 63;
    const int m     = bx >> 4;                  // 16 consecutive blocks share codebook m
    const int chunk = ((bx & 15) << 2) + w;
    const int R     = (chunk << 6) + lane;      // global row b, lane-local

    const float* __restrict__ cbm = cb + (size_t)m * (256 * 64);
    const f4*    __restrict__ cb4 = reinterpret_cast<const f4*>(cbm);

    // ---- block-level c2: thread tid handles code tid (also warms L1/L2) ----
    {
        const f4* crow = cb4 + tid * 16;
        float s0 = 0.f, s1 = 0.f, s2 = 0.f, s3 = 0.f;
        #pragma unroll
        for (int i = 0; i < 16; i += 4) {
            f4 a = crow[i], b = crow[i+1], c = crow[i+2], d = crow[i+3];
            s0 = fmaf(a.x,a.x,s0); s0 = fmaf(a.y,a.y,s0); s0 = fmaf(a.z,a.z,s0); s0 = fmaf(a.w,a.w,s0);
            s1 = fmaf(b.x,b.x,s1); s1 = fmaf(b.y,b.y,s1); s1 = fmaf(b.z,b.z,s1); s1 = fmaf(b.w,b.w,s1);
            s2 = fmaf(c.x,c.x,s2); s2 = fmaf(c.y,c.y,s2); s2 = fmaf(c.z,c.z,s2); s2 = fmaf(c.w,c.w,s2);
            s3 = fmaf(d.x,d.x,s3); s3 = fmaf(d.y,d.y,s3); s3 = fmaf(d.z,d.z,s3); s3 = fmaf(d.w,d.w,s3);
        }
        sC2[tid] = (s0 + s1) + (s2 + s3);
    }

    // ---- z row resident in 64 VGPRs ----
    f4 zv[16];
    {
        const f4* zr = reinterpret_cast<const f4*>(z + ((size_t)R * 64 + m) * 64);
        #pragma unroll
        for (int i = 0; i < 16; ++i) zv[i] = zr[i];
    }
    __syncthreads();

    // ---- rotating 4-quarter code buffer, prefetch depth ~3/4 of a k-step ----
    f4 A[4], B[4], C[4], D[4];
    #pragma unroll
    for (int i = 0; i < 4; ++i) {
        A[i] = cb4[i]; B[i] = cb4[4+i]; C[i] = cb4[8+i]; D[i] = cb4[12+i];
    }

    float best = 3.4e38f;
    int   bk   = 0;

    #pragma unroll 1
    for (int k = 0; k < 256; ++k) {
        const f4* nx = cb4 + (size_t)(k < 255 ? k + 1 : 255) * 16;  // clamped prefetch
        float a0 = 0.f, a1 = 0.f, a2 = 0.f, a3 = 0.f;
        QCONS(A, 0)  QLOAD(A, 0)
        QCONS(B, 4)  QLOAD(B, 4)
        QCONS(C, 8)  QLOAD(C, 8)
        QCONS(D, 12) QLOAD(D, 12)
        float s    = (a0 + a1) + (a2 + a3);
        float dist = fmaf(-2.f, s, sC2[k]);   // z2 omitted: row-constant shift
        bool  lt   = dist < best;             // strict < => first-min tiebreak
        best = lt ? dist : best;
        bk   = lt ? k    : bk;
    }

    // ---- outputs: index, exact codebook copy, loss partial ----
    out[IDX_BASE + (size_t)R * 64 + m] = (float)bk;

    const f4* qrow = cb4 + (size_t)bk * 16;   // L1/L2-hot gather
    f4* orow = reinterpret_cast<f4*>(out + ((size_t)R * 64 + m) * 64);
    float l0 = 0.f, l1 = 0.f;
    #pragma unroll
    for (int i = 0; i < 16; ++i) {
        f4 q = qrow[i], t = zv[i];
        orow[i] = q;
        float d0 = q.x - t.x, d1 = q.y - t.y, d2 = q.z - t.z, d3 = q.w - t.w;
        l0 = fmaf(d0, d0, l0); l1 = fmaf(d1, d1, l1);
        l0 = fmaf(d2, d2, l0); l1 = fmaf(d3, d3, l1);
    }
    float lsum = l0 + l1;
    #pragma unroll
    for (int off = 1; off < 64; off <<= 1) lsum += __shfl_xor(lsum, off, 64);
    if (lane == 0) sW[w] = lsum;
    __syncthreads();
    if (tid == 0) partial[bx] = (sW[0] + sW[1]) + (sW[2] + sW[3]);
}

// ---- deterministic final reduction of 1024 block partials -> q_loss ----
__global__ __launch_bounds__(256) void pq_loss(const float* __restrict__ partial,
                                               float* __restrict__ out)
{
    __shared__ float sW[4];
    float s = (partial[threadIdx.x]       + partial[threadIdx.x + 256])
            + (partial[threadIdx.x + 512] + partial[threadIdx.x + 768]);
    #pragma unroll
    for (int off = 1; off < 64; off <<= 1) s += __shfl_xor(s, off, 64);
    if ((threadIdx.x & 63) == 0) sW[threadIdx.x >> 6] = s;
    __syncthreads();
    if (threadIdx.x == 0)
        out[LOSS_IDX] = ((sW[0] + sW[1]) + (sW[2] + sW[3])) * (1.25f / 16777216.0f);
}

extern "C" void kernel_launch(void* const* d_in, const int* in_sizes, int n_in,
                              void* d_out, int out_size, void* d_ws, size_t ws_size,
                              hipStream_t stream) {
    const float* zp  = (const float*)d_in[0];
    const float* cbp = (const float*)d_in[1];
    float* outp = (float*)d_out;
    float* part = (float*)d_ws;   // 1024 floats

    pq_main<<<dim3(1024), dim3(256), 0, stream>>>(zp, cbp, outp, part);
    pq_loss<<<dim3(1),    dim3(256), 0, stream>>>(part, outp);
}

// Round 4
// 155.342 us; speedup vs baseline: 2.0507x; 1.6476x over previous
//
#include <hip/hip_runtime.h>

#define IDX_BASE 16777216UL   // 4096*64*64
#define LOSS_IDX 17039360UL   // IDX_BASE + 4096*64

typedef float4 f4;

__device__ __forceinline__ void gload_lds16(const float* g, float* s) {
    __builtin_amdgcn_global_load_lds(
        (const __attribute__((address_space(1))) unsigned int*)g,
        (__attribute__((address_space(3))) unsigned int*)s, 16, 0, 0);
}

// ---- c2[m][k] = ||codebook[m][k]||^2 ----
__global__ __launch_bounds__(256) void pq_c2(const float* __restrict__ cb,
                                             float* __restrict__ c2) {
    int m = blockIdx.x, k = threadIdx.x;
    const f4* row = reinterpret_cast<const f4*>(cb + ((size_t)m * 256 + k) * 64);
    float s0 = 0.f, s1 = 0.f;
    #pragma unroll
    for (int i = 0; i < 16; i += 2) {
        f4 a = row[i], b = row[i + 1];
        s0 = fmaf(a.x,a.x,s0); s0 = fmaf(a.y,a.y,s0); s0 = fmaf(a.z,a.z,s0); s0 = fmaf(a.w,a.w,s0);
        s1 = fmaf(b.x,b.x,s1); s1 = fmaf(b.y,b.y,s1); s1 = fmaf(b.z,b.z,s1); s1 = fmaf(b.w,b.w,s1);
    }
    c2[m * 256 + k] = s0 + s1;
}

// Block = one m x 256 rows, 512 threads. Thread tile: 8 rows x 16 codes.
// LDS: cb 64KB (col ^ (k&15)) + z 64KB (col ^ ((r>>3)&7)), both f4-granular swizzle.
__global__ __launch_bounds__(512, 2) void pq_main(
    const float* __restrict__ z, const float* __restrict__ cb,
    const float* __restrict__ c2ws,
    float* __restrict__ out, float* __restrict__ partial)
{
    __shared__ f4 sC[256 * 16];   // 64 KB
    __shared__ f4 sZ[256 * 16];   // 64 KB
    __shared__ int sBest[256];
    __shared__ float sW[8];

    const int tid   = threadIdx.x;
    const int bx    = blockIdx.x;
    const int m     = bx >> 4;          // 16 consecutive blocks share codebook m
    const int chunk = bx & 15;
    const int cg    = tid & 15;         // code group: codes q*16+cg
    const int rg    = tid >> 4;         // row group [0,32): rows rg*8..rg*8+7
    const int w     = tid >> 6;
    const int lane  = tid & 63;

    const float* __restrict__ cbm = cb + (size_t)m * (256 * 64);

    // prefetch c2 for this thread's 16 codes (in flight during staging)
    float c2r[16];
    #pragma unroll
    for (int q = 0; q < 16; ++q) c2r[q] = c2ws[m * 256 + q * 16 + cg];

    // ---- stage codebook: linear LDS rows, source col pre-swizzled ^ (k&15) ----
    #pragma unroll
    for (int i = 0; i < 8; ++i) {
        int k0   = w * 32 + i * 4;            // 4 rows per wave-instr
        int krow = k0 + (lane >> 4);
        int gcol = (lane & 15) ^ (krow & 15);
        gload_lds16(cbm + krow * 64 + gcol * 4, (float*)&sC[k0 * 16]);
    }
    // ---- stage z tile: rows b = chunk*256 + r, source col ^ ((r>>3)&7) ----
    #pragma unroll
    for (int i = 0; i < 8; ++i) {
        int r0   = w * 32 + i * 4;
        int grow = r0 + (lane >> 4);
        int gcol = (lane & 15) ^ ((grow >> 3) & 7);
        const float* src = z + ((size_t)(chunk * 256 + grow) * 64 + m) * 64 + gcol * 4;
        gload_lds16(src, (float*)&sZ[r0 * 16]);
    }
    __syncthreads();

    // ---- acc init: fold -0.5*c2 (argmax of S-0.5*c2 == argmin of c2-2S, exact) ----
    float acc[8][16];
    #pragma unroll
    for (int q = 0; q < 16; ++q) {
        float iv = -0.5f * c2r[q];
        #pragma unroll
        for (int p = 0; p < 8; ++p) acc[p][q] = iv;
    }

    const int zsw = rg & 7;                 // z swizzle const per thread
    const f4* zb  = &sZ[(rg * 8) * 16];
    const f4* cbs = &sC[cg * 16];           // code q*16+cg at offset q*256 + cg*16

    #pragma unroll 2
    for (int jg = 0; jg < 16; ++jg) {
        f4 zv[8];
        const int zc = jg ^ zsw;
        #pragma unroll
        for (int p = 0; p < 8; ++p) zv[p] = zb[p * 16 + zc];
        const int cc = jg ^ cg;
        f4 cv[8];
        #pragma unroll
        for (int q = 0; q < 8; ++q) cv[q] = cbs[q * 256 + cc];
        #pragma unroll
        for (int q = 0; q < 8; ++q) {
            #pragma unroll
            for (int p = 0; p < 8; ++p) {
                acc[p][q] = fmaf(zv[p].x, cv[q].x, acc[p][q]);
                acc[p][q] = fmaf(zv[p].y, cv[q].y, acc[p][q]);
                acc[p][q] = fmaf(zv[p].z, cv[q].z, acc[p][q]);
                acc[p][q] = fmaf(zv[p].w, cv[q].w, acc[p][q]);
            }
        }
        #pragma unroll
        for (int q = 0; q < 8; ++q) cv[q] = cbs[(q + 8) * 256 + cc];
        #pragma unroll
        for (int q = 0; q < 8; ++q) {
            #pragma unroll
            for (int p = 0; p < 8; ++p) {
                acc[p][q + 8] = fmaf(zv[p].x, cv[q].x, acc[p][q + 8]);
                acc[p][q + 8] = fmaf(zv[p].y, cv[q].y, acc[p][q + 8]);
                acc[p][q + 8] = fmaf(zv[p].z, cv[q].z, acc[p][q + 8]);
                acc[p][q + 8] = fmaf(zv[p].w, cv[q].w, acc[p][q + 8]);
            }
        }
    }

    // ---- per-thread argmax (q ascending => k ascending => first-min tiebreak) ----
    float bv[8]; int bk[8];
    #pragma unroll
    for (int p = 0; p < 8; ++p) { bv[p] = acc[p][0]; bk[p] = cg; }
    #pragma unroll
    for (int q = 1; q < 16; ++q) {
        #pragma unroll
        for (int p = 0; p < 8; ++p) {
            if (acc[p][q] > bv[p]) { bv[p] = acc[p][q]; bk[p] = q * 16 + cg; }
        }
    }
    // ---- reduce across 16 code-groups (shfl_xor stays within 16-lane group) ----
    #pragma unroll
    for (int off = 1; off < 16; off <<= 1) {
        #pragma unroll
        for (int p = 0; p < 8; ++p) {
            float ov = __shfl_xor(bv[p], off, 64);
            int   ok = __shfl_xor(bk[p], off, 64);
            if (ov > bv[p] || (ov == bv[p] && ok < bk[p])) { bv[p] = ov; bk[p] = ok; }
        }
    }
    if (cg == 0) {
        #pragma unroll
        for (int p = 0; p < 8; ++p) sBest[rg * 8 + p] = bk[p];
    }
    __syncthreads();

    // ---- outputs: quantized (exact global-codebook copy), index, loss partial ----
    float lsum = 0.f;
    {
        int row = tid >> 1;
        int h   = tid & 1;
        int k   = sBest[row];
        int b   = chunk * 256 + row;
        int rsw = (row >> 3) & 7;
        const f4* q4 = reinterpret_cast<const f4*>(cbm + (size_t)k * 64) + h * 8;
        f4*       o4 = reinterpret_cast<f4*>(out + ((size_t)b * 64 + m) * 64) + h * 8;
        float l0 = 0.f, l1 = 0.f;
        #pragma unroll
        for (int c = 0; c < 8; ++c) {
            f4 qv = q4[c];
            f4 zv = sZ[row * 16 + (((h << 3) + c) ^ rsw)];
            o4[c] = qv;
            float d0 = qv.x - zv.x, d1 = qv.y - zv.y, d2 = qv.z - zv.z, d3 = qv.w - zv.w;
            l0 = fmaf(d0, d0, l0); l1 = fmaf(d1, d1, l1);
            l0 = fmaf(d2, d2, l0); l1 = fmaf(d3, d3, l1);
        }
        lsum = l0 + l1;
    }
    if (tid < 256) {
        int b = chunk * 256 + tid;
        out[IDX_BASE + (size_t)b * 64 + m] = (float)sBest[tid];
    }
    #pragma unroll
    for (int off = 1; off < 64; off <<= 1) lsum += __shfl_xor(lsum, off, 64);
    if (lane == 0) sW[w] = lsum;
    __syncthreads();
    if (tid == 0) {
        float t = 0.f;
        #pragma unroll
        for (int i = 0; i < 8; ++i) t += sW[i];
        partial[bx] = t;
    }
}

// ---- deterministic final reduction of 1024 block partials -> q_loss ----
__global__ __launch_bounds__(256) void pq_loss(const float* __restrict__ partial,
                                               float* __restrict__ out)
{
    __shared__ float sW[4];
    float s = (partial[threadIdx.x]       + partial[threadIdx.x + 256])
            + (partial[threadIdx.x + 512] + partial[threadIdx.x + 768]);
    #pragma unroll
    for (int off = 1; off < 64; off <<= 1) s += __shfl_xor(s, off, 64);
    if ((threadIdx.x & 63) == 0) sW[threadIdx.x >> 6] = s;
    __syncthreads();
    if (threadIdx.x == 0)
        out[LOSS_IDX] = ((sW[0] + sW[1]) + (sW[2] + sW[3])) * (1.25f / 16777216.0f);
}

extern "C" void kernel_launch(void* const* d_in, const int* in_sizes, int n_in,
                              void* d_out, int out_size, void* d_ws, size_t ws_size,
                              hipStream_t stream) {
    const float* zp  = (const float*)d_in[0];
    const float* cbp = (const float*)d_in[1];
    float* outp = (float*)d_out;
    float* c2ws = (float*)d_ws;                  // 64*256 floats = 64 KB
    float* part = (float*)d_ws + 64 * 256;       // 1024 floats

    pq_c2  <<<dim3(64),   dim3(256), 0, stream>>>(cbp, c2ws);
    pq_main<<<dim3(1024), dim3(512), 0, stream>>>(zp, cbp, c2ws, outp, part);
    pq_loss<<<dim3(1),    dim3(256), 0, stream>>>(part, outp);
}